// Round 7
// baseline (245.620 us; speedup 1.0000x reference)
//
#include <hip/hip_runtime.h>
#include <math.h>

static constexpr int NNODE = 4096;
static constexpr int HDIM  = 256;
static constexpr int DIN   = 128;
static constexpr int HEADS = 8;
static constexpr int SPLIT = 4;     // attention key-split

using short8 = __attribute__((ext_vector_type(8))) short;
using f32x4  = __attribute__((ext_vector_type(4))) float;

__device__ inline unsigned short bfr(float x) {   // RNE fp32->bf16
    union { float f; unsigned u; } v; v.f = x;
    unsigned r = v.u + 0x7FFFu + ((v.u >> 16) & 1u);
    return (unsigned short)(r >> 16);
}
__device__ inline float bf2f(unsigned short u) {
    union { unsigned u; float f; } v; v.u = (unsigned)u << 16; return v.f;
}
__device__ inline unsigned cvt_pk_bf16(float lo, float hi) {
    unsigned r;
    asm("v_cvt_pk_bf16_f32 %0, %1, %2" : "=v"(r) : "v"(lo), "v"(hi));
    return r;
}

// scale/sqrt(32) folded with log2(e): softmax computed in exp2 domain
static constexpr float QSCALE_LOG2 = 0.25503527f;   // 0.176776695 * 1.442695041

// ---------------------------------------------------------------------------
__global__ void k_deg(const int* __restrict__ ei, int* __restrict__ degi, int E) {
    int e = blockIdx.x * 256 + threadIdx.x;
    if (e < E) atomicAdd(&degi[ei[E + e]], 1);
}

__global__ __launch_bounds__(256) void k_scan_norm(const int* __restrict__ degi,
        int* __restrict__ off, int* __restrict__ cursor,
        float* __restrict__ dinv, float* __restrict__ invdeg) {
    __shared__ int partial[256];
    __shared__ int basesh[256];
    int t = threadIdx.x;
    int local[16];
    int s = 0;
    #pragma unroll
    for (int i = 0; i < 16; ++i) { local[i] = degi[t * 16 + i]; s += local[i]; }
    partial[t] = s;
    __syncthreads();
    if (t == 0) {
        int run = 0;
        for (int i = 0; i < 256; ++i) { basesh[i] = run; run += partial[i]; }
    }
    __syncthreads();
    int b = basesh[t];
    #pragma unroll
    for (int i = 0; i < 16; ++i) {
        int n = t * 16 + i;
        off[n] = b; cursor[n] = b; b += local[i];
        float d = (float)local[i] + 1.0f;
        dinv[n]   = rsqrtf(d);
        invdeg[n] = 1.0f / d;
    }
}

__global__ void k_fill(const int* __restrict__ ei, int* __restrict__ cursor,
                       int* __restrict__ csr, int E) {
    int e = blockIdx.x * 256 + threadIdx.x;
    if (e < E) {
        int d = ei[E + e];
        int p = atomicAdd(&cursor[d], 1);
        csr[p] = ei[e];
    }
}

// ---------------------------------------------------------------------------
// weight + x prep: bf16 convert (+ transpose GCN weights to [N][K]),
// concat fp1/pd1. Grid covers 557056 virtual slots.
__global__ __launch_bounds__(256) void k_prep(
        const float* __restrict__ W1, const float* __restrict__ W2,
        const float* __restrict__ W3, const float* __restrict__ in_w,
        const float* __restrict__ outw, const float* __restrict__ fp1w,
        const float* __restrict__ pd1w, const float* __restrict__ fp1b,
        const float* __restrict__ pd1b, const float* __restrict__ x,
        unsigned short* __restrict__ W1t, unsigned short* __restrict__ W2t,
        unsigned short* __restrict__ W3t, unsigned short* __restrict__ in_wb,
        unsigned short* __restrict__ outwb, unsigned short* __restrict__ wcatb,
        float* __restrict__ bcat, unsigned short* __restrict__ xb) {
    int idx = blockIdx.x * 256 + threadIdx.x;
    if (idx < 32768) {                       // W1 [128][256] -> W1t [256][128]
        int c = idx >> 7, k = idx & 127;
        W1t[idx] = bfr(W1[(size_t)k * 256 + c]);
    } else if (idx < 98304) {                // W2 [256][256] -> W2t
        int j = idx - 32768; int c = j >> 8, k = j & 255;
        W2t[j] = bfr(W2[(size_t)k * 256 + c]);
    } else if (idx < 163840) {
        int j = idx - 98304; int c = j >> 8, k = j & 255;
        W3t[j] = bfr(W3[(size_t)k * 256 + c]);
    } else if (idx < 360448) {               // in_w already [768][256]
        int j = idx - 163840;
        in_wb[j] = bfr(in_w[j]);
    } else if (idx < 425984) {               // outw already [256][256]
        int j = idx - 360448;
        outwb[j] = bfr(outw[j]);
    } else if (idx < 491520) {               // wcat = [fp1w; pd1w]
        int j = idx - 425984;
        int row = j >> 8, k = j & 255;
        wcatb[j] = bfr(row < 128 ? fp1w[(size_t)row * 256 + k]
                                 : pd1w[(size_t)(row - 128) * 256 + k]);
        if (j < 256) bcat[j] = (j < 128) ? fp1b[j] : pd1b[j - 128];
    } else if (idx < 557056) {               // x -> bf16, 8 elems/thread
        int i = (idx - 491520) * 8;
        float4 a = *(const float4*)&x[i];
        float4 b = *(const float4*)&x[i + 4];
        short8 o;
        o[0]=(short)bfr(a.x); o[1]=(short)bfr(a.y); o[2]=(short)bfr(a.z); o[3]=(short)bfr(a.w);
        o[4]=(short)bfr(b.x); o[5]=(short)bfr(b.y); o[6]=(short)bfr(b.z); o[7]=(short)bfr(b.w);
        *(short8*)&xb[i] = o;
    }
}

// ---------------------------------------------------------------------------
// bf16 MFMA GEMM: C[M=4096][Nout] = A_bf16 @ B_bf16^T (+bias) (+addsrc)
// A: [M][K] bf16. B: [Nout][K] bf16 (torch layout).
// Block 256 = 4 waves; block tile 64(M) x 32(N); wave tile 16 x 32.
// EPI: 0 = fp32 out, 1 = bf16 out,
// EPI 2 = qkv: q,k head-major [head][node][32] (q pre-scaled log2);
//              v TRANSPOSED [head][dh][node] (uint2 packed writes).
template<int K, int EPI, bool BIAS, bool ADD>
__global__ __launch_bounds__(256) void k_bgemm(
        const unsigned short* __restrict__ A, const unsigned short* __restrict__ B,
        const float* __restrict__ bias, const float* __restrict__ addsrc,
        void* __restrict__ P0, void* __restrict__ P1, void* __restrict__ P2,
        int Nout) {
    const int lane = threadIdx.x & 63, wave = threadIdx.x >> 6;
    const int ql = lane & 15, g = lane >> 4;
    const int m0w = blockIdx.y * 64 + wave * 16;
    const int n0 = blockIdx.x * 32;
    const unsigned short* ap = A + (size_t)(m0w + ql) * K + g * 8;
    const unsigned short* bp = B + (size_t)(n0 + ql) * K + g * 8;

    f32x4 acc[2] = {{0,0,0,0},{0,0,0,0}};
    #pragma unroll
    for (int k0 = 0; k0 < K; k0 += 32) {
        short8 a = *(const short8*)(ap + k0);
        #pragma unroll
        for (int nt = 0; nt < 2; ++nt) {
            short8 b = *(const short8*)(bp + (size_t)nt * 16 * K + k0);
            acc[nt] = __builtin_amdgcn_mfma_f32_16x16x32_bf16(a, b, acc[nt], 0, 0, 0);
        }
    }
    #pragma unroll
    for (int nt = 0; nt < 2; ++nt) {
        const int col = n0 + nt * 16 + ql;
        const float bv = BIAS ? bias[col] : 0.f;
        if (EPI == 2) {
            const int sec = col >> 8, cc = col & 255;
            const int head = cc >> 5, dh = cc & 31;
            if (sec == 2) {
                // V^T [head][dh][node]: rows m0w+g*4..+3 contiguous -> uint2
                unsigned short* dst = (unsigned short*)P2
                    + ((size_t)head * 32 + dh) * NNODE + m0w + g * 4;
                uint2 pk;
                pk.x = cvt_pk_bf16(acc[nt][0] + bv, acc[nt][1] + bv);
                pk.y = cvt_pk_bf16(acc[nt][2] + bv, acc[nt][3] + bv);
                *(uint2*)dst = pk;
            } else {
                unsigned short* dst = (unsigned short*)(sec == 0 ? P0 : P1);
                const float sc = (sec == 0) ? QSCALE_LOG2 : 1.0f;
                #pragma unroll
                for (int i = 0; i < 4; ++i) {
                    int row = m0w + g * 4 + i;
                    dst[((size_t)head * NNODE + row) * 32 + dh] = bfr((acc[nt][i] + bv) * sc);
                }
            }
        } else if (EPI == 1) {
            unsigned short* Cb = (unsigned short*)P0;
            #pragma unroll
            for (int i = 0; i < 4; ++i) {
                int row = m0w + g * 4 + i;
                float v = acc[nt][i] + bv;
                if (ADD) v += addsrc[(size_t)row * Nout + col];
                Cb[(size_t)row * Nout + col] = bfr(v);
            }
        } else {
            float* Cf = (float*)P0;
            #pragma unroll
            for (int i = 0; i < 4; ++i) {
                int row = m0w + g * 4 + i;
                float v = acc[nt][i] + bv;
                if (ADD) v += addsrc[(size_t)row * Nout + col];
                Cf[(size_t)row * Nout + col] = v;
            }
        }
    }
}

// ---------------------------------------------------------------------------
// CSR gather over bf16 hW. MODE 0: write bf16(relu(val)). MODE 1: fp32 + bf16.
template<int MODE>
__global__ __launch_bounds__(256) void k_gather(const unsigned short* __restrict__ hW,
        const int* __restrict__ csr, const int* __restrict__ off,
        const int* __restrict__ degi, const float* __restrict__ dinv,
        const float* __restrict__ invdeg, const float* __restrict__ bias,
        float* __restrict__ aggf, unsigned short* __restrict__ aggb) {
    const int n = blockIdx.x;
    const int c = threadIdx.x;
    const int start = off[n];
    const int cnt = degi[n];
    __shared__ int   sidx[64];
    __shared__ float swht[64];
    float acc = 0.f;
    for (int k0 = 0; k0 < cnt; k0 += 64) {
        __syncthreads();
        if (c < 64 && k0 + c < cnt) {
            int s = csr[start + k0 + c];
            sidx[c] = s;
            swht[c] = dinv[s];
        }
        __syncthreads();
        int lim = min(64, cnt - k0);
        for (int k = 0; k < lim; ++k)
            acc += bf2f(hW[(size_t)sidx[k] * HDIM + c]) * swht[k];
    }
    float val = acc * dinv[n] + bf2f(hW[(size_t)n * HDIM + c]) * invdeg[n] + bias[c];
    if (MODE == 0) {
        aggb[(size_t)n * HDIM + c] = bfr(fmaxf(val, 0.f));
    } else {
        aggf[(size_t)n * HDIM + c] = val;
        aggb[(size_t)n * HDIM + c] = bfr(val);
    }
}

// ---------------------------------------------------------------------------
// MFMA flash attention, split-K. Block = 1 head x 64 q x 1 of 4 splits.
// K and V^T fragments read DIRECT from global (L2-resident); only P goes
// through per-wave LDS; ZERO barriers in the loop. Softmax in log2 domain.
__global__ __launch_bounds__(256) void k_attn_mfma(const unsigned short* __restrict__ qh,
        const unsigned short* __restrict__ kh, const unsigned short* __restrict__ vt,
        unsigned short* __restrict__ po, float* __restrict__ pm, float* __restrict__ pl) {
    const int hd = blockIdx.x;
    const int qb = blockIdx.y;
    const int z  = blockIdx.z;
    const int tid = threadIdx.x;
    const int wave = tid >> 6, lane = tid & 63;
    const int ql = lane & 15, g = lane >> 4;

    __shared__ unsigned short Plds[4][16 * 72];   // per wave [q][key] pad 72

    const unsigned short* khh = kh + (size_t)hd * NNODE * 32;
    const unsigned short* vtt = vt + (size_t)hd * 32 * NNODE;
    const int row = qb * 64 + wave * 16 + ql;
    short8 qf = *(const short8*)(qh + ((size_t)hd * NNODE + row) * 32 + g * 8);

    // per-lane V^T row pointers (A-operand: lane ql = dh-within-tile)
    const unsigned short* v0p = vtt + (size_t)ql * NNODE + g * 8;         // dh 0-15
    const unsigned short* v1p = vtt + (size_t)(16 + ql) * NNODE + g * 8;  // dh 16-31

    f32x4 oa0 = {0,0,0,0}, oa1 = {0,0,0,0};
    float m = -INFINITY, l = 0.f;

    const int TPS = NNODE / 64 / SPLIT;
    const int t0 = z * TPS;

    for (int kt = t0; kt < t0 + TPS; ++kt) {
        // S^T[64k x 16q]: K fragments straight from global
        f32x4 st[4];
        #pragma unroll
        for (int t = 0; t < 4; ++t) {
            short8 kf = *(const short8*)(khh + (size_t)(kt * 64 + t * 16 + ql) * 32 + g * 8);
            st[t] = __builtin_amdgcn_mfma_f32_16x16x32_bf16(kf, qf, (f32x4){0,0,0,0}, 0, 0, 0);
        }

        float mloc = -INFINITY;
        #pragma unroll
        for (int t = 0; t < 4; ++t)
            mloc = fmaxf(mloc, fmaxf(fmaxf(st[t][0], st[t][1]), fmaxf(st[t][2], st[t][3])));
        mloc = fmaxf(mloc, __shfl_xor(mloc, 16));
        mloc = fmaxf(mloc, __shfl_xor(mloc, 32));

        // defer-max (T13, log2 units): P bounded by 2^8 when deferred
        if (!__all(mloc <= m + 8.f)) {
            float mnew = fmaxf(m, mloc);
            float corr = exp2f(m - mnew);   // first tile: exp2(-inf)=0
            l *= corr; oa0 *= corr; oa1 *= corr; m = mnew;
        }

        float ll = 0.f;
        unsigned pw[8];
        #pragma unroll
        for (int t = 0; t < 4; ++t) {
            float p0 = exp2f(st[t][0] - m);
            float p1 = exp2f(st[t][1] - m);
            float p2 = exp2f(st[t][2] - m);
            float p3 = exp2f(st[t][3] - m);
            ll += (p0 + p1) + (p2 + p3);
            pw[t * 2 + 0] = cvt_pk_bf16(p0, p1);
            pw[t * 2 + 1] = cvt_pk_bf16(p2, p3);
        }
        ll += __shfl_xor(ll, 16);
        ll += __shfl_xor(ll, 32);
        l += ll;

        #pragma unroll
        for (int t = 0; t < 4; ++t) {
            uint2 w2; w2.x = pw[t * 2 + 0]; w2.y = pw[t * 2 + 1];
            *(uint2*)&Plds[wave][ql * 72 + t * 16 + g * 4] = w2;
        }

        // O^T += V^T · P^T, V^T fragments direct from global
        #pragma unroll
        for (int c = 0; c < 2; ++c) {
            short8 pf = *(const short8*)&Plds[wave][ql * 72 + c * 32 + g * 8];
            short8 v0 = *(const short8*)(v0p + kt * 64 + c * 32);
            short8 v1 = *(const short8*)(v1p + kt * 64 + c * 32);
            oa0 = __builtin_amdgcn_mfma_f32_16x16x32_bf16(v0, pf, oa0, 0, 0, 0);
            oa1 = __builtin_amdgcn_mfma_f32_16x16x32_bf16(v1, pf, oa1, 0, 0, 0);
        }
    }

    const size_t pidx = ((size_t)hd * NNODE + row) * SPLIT + z;
    unsigned short* pp = po + pidx * 32;
    uint2 r0, r1;
    r0.x = cvt_pk_bf16(oa0[0], oa0[1]); r0.y = cvt_pk_bf16(oa0[2], oa0[3]);
    r1.x = cvt_pk_bf16(oa1[0], oa1[1]); r1.y = cvt_pk_bf16(oa1[2], oa1[3]);
    *(uint2*)&pp[g * 4]      = r0;
    *(uint2*)&pp[16 + g * 4] = r1;
    if (g == 0) { pm[pidx] = m; pl[pidx] = l; }
}

__global__ __launch_bounds__(256) void k_attn_merge(const unsigned short* __restrict__ po,
        const float* __restrict__ pm, const float* __restrict__ pl,
        unsigned short* __restrict__ ob) {
    int idx = blockIdx.x * 256 + threadIdx.x;     // NNODE*HDIM
    int row = idx >> 8, c = idx & 255;
    int hd = c >> 5, dh = c & 31;
    size_t b4 = ((size_t)hd * NNODE + row) * SPLIT;
    float m0 = pm[b4+0], m1 = pm[b4+1], m2 = pm[b4+2], m3 = pm[b4+3];
    float M = fmaxf(fmaxf(m0, m1), fmaxf(m2, m3));
    float w0 = exp2f(m0 - M), w1 = exp2f(m1 - M);
    float w2 = exp2f(m2 - M), w3 = exp2f(m3 - M);
    float L = pl[b4]*w0 + pl[b4+1]*w1 + pl[b4+2]*w2 + pl[b4+3]*w3;
    float v = bf2f(po[(b4+0)*32 + dh])*w0 + bf2f(po[(b4+1)*32 + dh])*w1
            + bf2f(po[(b4+2)*32 + dh])*w2 + bf2f(po[(b4+3)*32 + dh])*w3;
    ob[idx] = bfr(v / L);
}

// ---------------------------------------------------------------------------
// heads layer-2 epilogue: one wave per node; th = [4096][256] pre-relu fp32.
__global__ __launch_bounds__(256) void k_heads2(const float* __restrict__ th,
        const float* __restrict__ fp2w, const float* __restrict__ fp2b,
        const float* __restrict__ pd2w, const float* __restrict__ pd2b,
        float* __restrict__ out) {
    const int wave = threadIdx.x >> 6, lane = threadIdx.x & 63;
    const int n = blockIdx.x * 4 + wave;
    const int half = lane >> 5;        // 0 = fp head, 1 = pd head
    const int li = lane & 31;
    float4 h4 = *(const float4*)&th[(size_t)n * HDIM + half * 128 + li * 4];
    h4.x = fmaxf(h4.x, 0.f); h4.y = fmaxf(h4.y, 0.f);
    h4.z = fmaxf(h4.z, 0.f); h4.w = fmaxf(h4.w, 0.f);
    float lf[3];
    float lp[10];
    #pragma unroll
    for (int j = 0; j < 10; ++j) {
        float partial = 0.f;
        if (half == 0) {
            if (j < 3) {
                float4 wv = *(const float4*)&fp2w[j * 128 + li * 4];
                partial = h4.x*wv.x + h4.y*wv.y + h4.z*wv.z + h4.w*wv.w;
            }
        } else {
            float4 wv = *(const float4*)&pd2w[j * 128 + li * 4];
            partial = h4.x*wv.x + h4.y*wv.y + h4.z*wv.z + h4.w*wv.w;
        }
        #pragma unroll
        for (int d = 1; d < 32; d <<= 1) partial += __shfl_xor(partial, d);
        if (j < 3) lf[j] = partial;
        lp[j] = partial;
    }
    if (lane == 0) {
        float l0 = lf[0] + fp2b[0], l1 = lf[1] + fp2b[1], l2 = lf[2] + fp2b[2];
        float mx = fmaxf(l0, fmaxf(l1, l2));
        float e0 = __expf(l0 - mx), e1 = __expf(l1 - mx), e2 = __expf(l2 - mx);
        float inv = 1.f / (e0 + e1 + e2);
        out[(size_t)n * 3 + 0] = e0 * inv;
        out[(size_t)n * 3 + 1] = e1 * inv;
        out[(size_t)n * 3 + 2] = e2 * inv;
    } else if (lane == 32) {
        #pragma unroll
        for (int j = 0; j < 10; ++j)
            out[(size_t)NNODE * 3 + (size_t)n * 10 + j] =
                1.f / (1.f + __expf(-(lp[j] + pd2b[j])));
    }
}

// ---------------------------------------------------------------------------
extern "C" void kernel_launch(void* const* d_in, const int* in_sizes, int n_in,
                              void* d_out, int out_size, void* d_ws, size_t ws_size,
                              hipStream_t stream) {
    const float* x    = (const float*)d_in[0];
    const int*   ei   = (const int*)  d_in[1];
    const float* W1   = (const float*)d_in[2];
    const float* b1   = (const float*)d_in[3];
    const float* W2   = (const float*)d_in[4];
    const float* b2   = (const float*)d_in[5];
    const float* W3   = (const float*)d_in[6];
    const float* b3   = (const float*)d_in[7];
    const float* in_w = (const float*)d_in[8];
    const float* in_b = (const float*)d_in[9];
    const float* outw = (const float*)d_in[10];
    const float* outb = (const float*)d_in[11];
    const float* fp1w = (const float*)d_in[12];
    const float* fp1b = (const float*)d_in[13];
    const float* fp2w = (const float*)d_in[14];
    const float* fp2b = (const float*)d_in[15];
    const float* pd1w = (const float*)d_in[16];
    const float* pd1b = (const float*)d_in[17];
    const float* pd2w = (const float*)d_in[18];
    const float* pd2b = (const float*)d_in[19];
    float* out = (float*)d_out;

    const int E = in_sizes[1] / 2;

    // workspace layout (256B-aligned chunks)
    char* w = (char*)d_ws;
    auto alloc = [&](size_t bytes) {
        char* p = w; w += (bytes + 255) & ~(size_t)255; return p;
    };
    int*   degi   = (int*)alloc(NNODE * 4);
    int*   off    = (int*)alloc(NNODE * 4);
    int*   cursor = (int*)alloc(NNODE * 4);
    int*   csr    = (int*)alloc((size_t)E * 4);
    float* dinv   = (float*)alloc(NNODE * 4);
    float* invdeg = (float*)alloc(NNODE * 4);
    unsigned short* W1t   = (unsigned short*)alloc(256 * 128 * 2);
    unsigned short* W2t   = (unsigned short*)alloc(256 * 256 * 2);
    unsigned short* W3t   = (unsigned short*)alloc(256 * 256 * 2);
    unsigned short* in_wb = (unsigned short*)alloc(768 * 256 * 2);
    unsigned short* outwb = (unsigned short*)alloc(256 * 256 * 2);
    unsigned short* wcatb = (unsigned short*)alloc(256 * 256 * 2);
    float* bcat  = (float*)alloc(256 * 4);
    unsigned short* xb    = (unsigned short*)alloc((size_t)NNODE * DIN * 2);
    float* bufA  = (float*)alloc((size_t)NNODE * HDIM * 4);             // heads th
    unsigned short* bufAb = (unsigned short*)alloc((size_t)NNODE * HDIM * 2); // conv hW
    unsigned short* aggb1 = (unsigned short*)alloc((size_t)NNODE * HDIM * 2);
    unsigned short* aggb2 = (unsigned short*)alloc((size_t)NNODE * HDIM * 2);
    float* hf    = (float*)alloc((size_t)NNODE * HDIM * 4);             // h fp32 residual
    unsigned short* hb    = (unsigned short*)alloc((size_t)NNODE * HDIM * 2);
    unsigned short* qh    = (unsigned short*)alloc((size_t)HEADS * NNODE * 32 * 2);
    unsigned short* kh    = (unsigned short*)alloc((size_t)HEADS * NNODE * 32 * 2);
    unsigned short* vt    = (unsigned short*)alloc((size_t)HEADS * 32 * NNODE * 2);
    unsigned short* po    = (unsigned short*)alloc((size_t)HEADS * NNODE * SPLIT * 32 * 2);
    float* pm    = (float*)alloc((size_t)HEADS * NNODE * SPLIT * 4);
    float* pl    = (float*)alloc((size_t)HEADS * NNODE * SPLIT * 4);
    unsigned short* ob    = (unsigned short*)alloc((size_t)NNODE * HDIM * 2);
    unsigned short* hfinb = (unsigned short*)alloc((size_t)NNODE * HDIM * 2);

    // CSR build + norms + weight/x prep
    hipMemsetAsync(degi, 0, NNODE * sizeof(int), stream);
    k_deg<<<(E + 255) / 256, 256, 0, stream>>>(ei, degi, E);
    k_scan_norm<<<1, 256, 0, stream>>>(degi, off, cursor, dinv, invdeg);
    k_fill<<<(E + 255) / 256, 256, 0, stream>>>(ei, cursor, csr, E);
    k_prep<<<2176, 256, 0, stream>>>(W1, W2, W3, in_w, outw, fp1w, pd1w, fp1b, pd1b, x,
                                     W1t, W2t, W3t, in_wb, outwb, wcatb, bcat, xb);

    dim3 g256(HDIM / 32, NNODE / 64);   // (8,64)
    dim3 g768(768 / 32, NNODE / 64);    // (24,64)

    // conv1
    k_bgemm<DIN, 1, false, false><<<g256, 256, 0, stream>>>(xb, W1t, nullptr, nullptr, bufAb, nullptr, nullptr, HDIM);
    k_gather<0><<<NNODE, 256, 0, stream>>>(bufAb, csr, off, degi, dinv, invdeg, b1, nullptr, aggb1);
    // conv2
    k_bgemm<HDIM, 1, false, false><<<g256, 256, 0, stream>>>(aggb1, W2t, nullptr, nullptr, bufAb, nullptr, nullptr, HDIM);
    k_gather<0><<<NNODE, 256, 0, stream>>>(bufAb, csr, off, degi, dinv, invdeg, b2, nullptr, aggb2);
    // conv3
    k_bgemm<HDIM, 1, false, false><<<g256, 256, 0, stream>>>(aggb2, W3t, nullptr, nullptr, bufAb, nullptr, nullptr, HDIM);
    k_gather<1><<<NNODE, 256, 0, stream>>>(bufAb, csr, off, degi, dinv, invdeg, b3, hf, hb);

    // MHA: qkv GEMM writes q/k head-major + V TRANSPOSED (log2-domain q)
    k_bgemm<HDIM, 2, true, false><<<g768, 256, 0, stream>>>(hb, in_wb, in_b, nullptr, qh, kh, vt, 768);
    k_attn_mfma<<<dim3(HEADS, NNODE / 64, SPLIT), 256, 0, stream>>>(qh, kh, vt, po, pm, pl);
    k_attn_merge<<<(NNODE * HDIM) / 256, 256, 0, stream>>>(po, pm, pl, ob);
    // out-proj + residual -> bf16 h_final
    k_bgemm<HDIM, 1, true, true><<<g256, 256, 0, stream>>>(ob, outwb, outb, hf, hfinb, nullptr, nullptr, HDIM);

    // MLP heads: layer 1 as GEMM (fp32 out), layer 2 epilogue
    k_bgemm<HDIM, 0, true, false><<<g256, 256, 0, stream>>>(hfinb, wcatb, bcat, nullptr, bufA, nullptr, nullptr, HDIM);
    k_heads2<<<NNODE / 4, 256, 0, stream>>>(bufA, fp2w, fp2b, pd2w, pd2b, out);
}

// Round 8
// 206.402 us; speedup vs baseline: 1.1900x; 1.1900x over previous
//
#include <hip/hip_runtime.h>
#include <math.h>

static constexpr int NNODE = 4096;
static constexpr int HDIM  = 256;
static constexpr int DIN   = 128;
static constexpr int HEADS = 8;
static constexpr int SPLIT = 4;     // attention key-split

using short8 = __attribute__((ext_vector_type(8))) short;
using f32x4  = __attribute__((ext_vector_type(4))) float;

__device__ inline unsigned short bfr(float x) {   // RNE fp32->bf16
    union { float f; unsigned u; } v; v.f = x;
    unsigned r = v.u + 0x7FFFu + ((v.u >> 16) & 1u);
    return (unsigned short)(r >> 16);
}
__device__ inline float bf2f(unsigned short u) {
    union { unsigned u; float f; } v; v.u = (unsigned)u << 16; return v.f;
}
__device__ inline unsigned cvt_pk_bf16(float lo, float hi) {
    unsigned r;
    asm("v_cvt_pk_bf16_f32 %0, %1, %2" : "=v"(r) : "v"(lo), "v"(hi));
    return r;
}

// scale/sqrt(32) folded with log2(e): softmax computed in exp2 domain
static constexpr float QSCALE_LOG2 = 0.25503527f;   // 0.176776695 * 1.442695041

// ---------------------------------------------------------------------------
__global__ void k_deg(const int* __restrict__ ei, int* __restrict__ degi, int E) {
    int e = blockIdx.x * 256 + threadIdx.x;
    if (e < E) atomicAdd(&degi[ei[E + e]], 1);
}

__global__ __launch_bounds__(256) void k_scan_norm(const int* __restrict__ degi,
        int* __restrict__ off, int* __restrict__ cursor,
        float* __restrict__ dinv, float* __restrict__ invdeg) {
    __shared__ int partial[256];
    __shared__ int basesh[256];
    int t = threadIdx.x;
    int local[16];
    int s = 0;
    #pragma unroll
    for (int i = 0; i < 16; ++i) { local[i] = degi[t * 16 + i]; s += local[i]; }
    partial[t] = s;
    __syncthreads();
    if (t == 0) {
        int run = 0;
        for (int i = 0; i < 256; ++i) { basesh[i] = run; run += partial[i]; }
    }
    __syncthreads();
    int b = basesh[t];
    #pragma unroll
    for (int i = 0; i < 16; ++i) {
        int n = t * 16 + i;
        off[n] = b; cursor[n] = b; b += local[i];
        float d = (float)local[i] + 1.0f;
        dinv[n]   = rsqrtf(d);
        invdeg[n] = 1.0f / d;
    }
}

__global__ void k_fill(const int* __restrict__ ei, int* __restrict__ cursor,
                       int* __restrict__ csr, int E) {
    int e = blockIdx.x * 256 + threadIdx.x;
    if (e < E) {
        int d = ei[E + e];
        int p = atomicAdd(&cursor[d], 1);
        csr[p] = ei[e];
    }
}

// ---------------------------------------------------------------------------
// weight + x prep: bf16 convert (+ transpose GCN weights to [N][K]),
// concat fp1/pd1. Grid covers 557056 virtual slots.
__global__ __launch_bounds__(256) void k_prep(
        const float* __restrict__ W1, const float* __restrict__ W2,
        const float* __restrict__ W3, const float* __restrict__ in_w,
        const float* __restrict__ outw, const float* __restrict__ fp1w,
        const float* __restrict__ pd1w, const float* __restrict__ fp1b,
        const float* __restrict__ pd1b, const float* __restrict__ x,
        unsigned short* __restrict__ W1t, unsigned short* __restrict__ W2t,
        unsigned short* __restrict__ W3t, unsigned short* __restrict__ in_wb,
        unsigned short* __restrict__ outwb, unsigned short* __restrict__ wcatb,
        float* __restrict__ bcat, unsigned short* __restrict__ xb) {
    int idx = blockIdx.x * 256 + threadIdx.x;
    if (idx < 32768) {                       // W1 [128][256] -> W1t [256][128]
        int c = idx >> 7, k = idx & 127;
        W1t[idx] = bfr(W1[(size_t)k * 256 + c]);
    } else if (idx < 98304) {                // W2 [256][256] -> W2t
        int j = idx - 32768; int c = j >> 8, k = j & 255;
        W2t[j] = bfr(W2[(size_t)k * 256 + c]);
    } else if (idx < 163840) {
        int j = idx - 98304; int c = j >> 8, k = j & 255;
        W3t[j] = bfr(W3[(size_t)k * 256 + c]);
    } else if (idx < 360448) {               // in_w already [768][256]
        int j = idx - 163840;
        in_wb[j] = bfr(in_w[j]);
    } else if (idx < 425984) {               // outw already [256][256]
        int j = idx - 360448;
        outwb[j] = bfr(outw[j]);
    } else if (idx < 491520) {               // wcat = [fp1w; pd1w]
        int j = idx - 425984;
        int row = j >> 8, k = j & 255;
        wcatb[j] = bfr(row < 128 ? fp1w[(size_t)row * 256 + k]
                                 : pd1w[(size_t)(row - 128) * 256 + k]);
        if (j < 256) bcat[j] = (j < 128) ? fp1b[j] : pd1b[j - 128];
    } else if (idx < 557056) {               // x -> bf16, 8 elems/thread
        int i = (idx - 491520) * 8;
        float4 a = *(const float4*)&x[i];
        float4 b = *(const float4*)&x[i + 4];
        short8 o;
        o[0]=(short)bfr(a.x); o[1]=(short)bfr(a.y); o[2]=(short)bfr(a.z); o[3]=(short)bfr(a.w);
        o[4]=(short)bfr(b.x); o[5]=(short)bfr(b.y); o[6]=(short)bfr(b.z); o[7]=(short)bfr(b.w);
        *(short8*)&xb[i] = o;
    }
}

// ---------------------------------------------------------------------------
// bf16 MFMA GEMM: C[M=4096][Nout] = A_bf16 @ B_bf16^T (+bias) (+addsrc)
// A: [M][K] bf16. B: [Nout][K] bf16 (torch layout).
// Block 256 = 4 waves; block tile 64(M) x 32(N); wave tile 16 x 32.
// EPI: 0 = fp32 out, 1 = bf16 out,
// EPI 2 = qkv: q,k head-major [head][node][32] (q pre-scaled log2);
//              v TRANSPOSED [head][dh][node] (uint2 packed writes).
template<int K, int EPI, bool BIAS, bool ADD>
__global__ __launch_bounds__(256) void k_bgemm(
        const unsigned short* __restrict__ A, const unsigned short* __restrict__ B,
        const float* __restrict__ bias, const float* __restrict__ addsrc,
        void* __restrict__ P0, void* __restrict__ P1, void* __restrict__ P2,
        int Nout) {
    const int lane = threadIdx.x & 63, wave = threadIdx.x >> 6;
    const int ql = lane & 15, g = lane >> 4;
    const int m0w = blockIdx.y * 64 + wave * 16;
    const int n0 = blockIdx.x * 32;
    const unsigned short* ap = A + (size_t)(m0w + ql) * K + g * 8;
    const unsigned short* bp = B + (size_t)(n0 + ql) * K + g * 8;

    f32x4 acc[2] = {{0,0,0,0},{0,0,0,0}};
    #pragma unroll
    for (int k0 = 0; k0 < K; k0 += 32) {
        short8 a = *(const short8*)(ap + k0);
        #pragma unroll
        for (int nt = 0; nt < 2; ++nt) {
            short8 b = *(const short8*)(bp + (size_t)nt * 16 * K + k0);
            acc[nt] = __builtin_amdgcn_mfma_f32_16x16x32_bf16(a, b, acc[nt], 0, 0, 0);
        }
    }
    #pragma unroll
    for (int nt = 0; nt < 2; ++nt) {
        const int col = n0 + nt * 16 + ql;
        const float bv = BIAS ? bias[col] : 0.f;
        if (EPI == 2) {
            const int sec = col >> 8, cc = col & 255;
            const int head = cc >> 5, dh = cc & 31;
            if (sec == 2) {
                // V^T [head][dh][node]: rows m0w+g*4..+3 contiguous -> uint2
                unsigned short* dst = (unsigned short*)P2
                    + ((size_t)head * 32 + dh) * NNODE + m0w + g * 4;
                uint2 pk;
                pk.x = cvt_pk_bf16(acc[nt][0] + bv, acc[nt][1] + bv);
                pk.y = cvt_pk_bf16(acc[nt][2] + bv, acc[nt][3] + bv);
                *(uint2*)dst = pk;
            } else {
                unsigned short* dst = (unsigned short*)(sec == 0 ? P0 : P1);
                const float sc = (sec == 0) ? QSCALE_LOG2 : 1.0f;
                #pragma unroll
                for (int i = 0; i < 4; ++i) {
                    int row = m0w + g * 4 + i;
                    dst[((size_t)head * NNODE + row) * 32 + dh] = bfr((acc[nt][i] + bv) * sc);
                }
            }
        } else if (EPI == 1) {
            unsigned short* Cb = (unsigned short*)P0;
            #pragma unroll
            for (int i = 0; i < 4; ++i) {
                int row = m0w + g * 4 + i;
                float v = acc[nt][i] + bv;
                if (ADD) v += addsrc[(size_t)row * Nout + col];
                Cb[(size_t)row * Nout + col] = bfr(v);
            }
        } else {
            float* Cf = (float*)P0;
            #pragma unroll
            for (int i = 0; i < 4; ++i) {
                int row = m0w + g * 4 + i;
                float v = acc[nt][i] + bv;
                if (ADD) v += addsrc[(size_t)row * Nout + col];
                Cf[(size_t)row * Nout + col] = v;
            }
        }
    }
}

// ---------------------------------------------------------------------------
// CSR gather over bf16 hW. MODE 0: write bf16(relu(val)). MODE 1: fp32 + bf16.
template<int MODE>
__global__ __launch_bounds__(256) void k_gather(const unsigned short* __restrict__ hW,
        const int* __restrict__ csr, const int* __restrict__ off,
        const int* __restrict__ degi, const float* __restrict__ dinv,
        const float* __restrict__ invdeg, const float* __restrict__ bias,
        float* __restrict__ aggf, unsigned short* __restrict__ aggb) {
    const int n = blockIdx.x;
    const int c = threadIdx.x;
    const int start = off[n];
    const int cnt = degi[n];
    __shared__ int   sidx[64];
    __shared__ float swht[64];
    float acc = 0.f;
    for (int k0 = 0; k0 < cnt; k0 += 64) {
        __syncthreads();
        if (c < 64 && k0 + c < cnt) {
            int s = csr[start + k0 + c];
            sidx[c] = s;
            swht[c] = dinv[s];
        }
        __syncthreads();
        int lim = min(64, cnt - k0);
        for (int k = 0; k < lim; ++k)
            acc += bf2f(hW[(size_t)sidx[k] * HDIM + c]) * swht[k];
    }
    float val = acc * dinv[n] + bf2f(hW[(size_t)n * HDIM + c]) * invdeg[n] + bias[c];
    if (MODE == 0) {
        aggb[(size_t)n * HDIM + c] = bfr(fmaxf(val, 0.f));
    } else {
        aggf[(size_t)n * HDIM + c] = val;
        aggb[(size_t)n * HDIM + c] = bfr(val);
    }
}

// ---------------------------------------------------------------------------
// MFMA flash attention, split-K. Flat grid, head = bid&7 -> per-XCD L2
// affinity (one head's K/V/Q = 768 KB, L2-resident per XCD).
// K fragments direct from global (coalesced 1KB/wave); V^T staged to LDS
// with vector load + vector ds_write (double-buffered, 1 barrier/iter).
__global__ __launch_bounds__(256) void k_attn_mfma(const unsigned short* __restrict__ qh,
        const unsigned short* __restrict__ kh, const unsigned short* __restrict__ vt,
        unsigned short* __restrict__ po, float* __restrict__ pm, float* __restrict__ pl) {
    const int bid = blockIdx.x;
    const int hd = bid & 7;                     // XCD affinity: head h -> XCD h
    const int z  = (bid >> 3) & (SPLIT - 1);
    const int qb = bid >> 5;
    const int tid = threadIdx.x;
    const int wave = tid >> 6, lane = tid & 63;
    const int ql = lane & 15, g = lane >> 4;

    __shared__ unsigned short Vt[2][32 * 72];     // [dh][key] pad 72
    __shared__ unsigned short Plds[4][16 * 72];   // per wave [q][key] pad 72

    const unsigned short* khh = kh + (size_t)hd * NNODE * 32;
    const unsigned short* vtt = vt + (size_t)hd * 32 * NNODE;
    const int row = qb * 64 + wave * 16 + ql;
    short8 qf = *(const short8*)(qh + ((size_t)hd * NNODE + row) * 32 + g * 8);

    f32x4 oa0 = {0,0,0,0}, oa1 = {0,0,0,0};
    float m = -INFINITY, l = 0.f;

    // V^T staging: thread -> dh = tid>>3 (0..31), chunk = tid&7 (0..7)
    const int sdh = tid >> 3, sch = (tid & 7) * 8;
    const unsigned short* vsrc = vtt + (size_t)sdh * NNODE + sch;
    const int TPS = NNODE / 64 / SPLIT;
    const int t0 = z * TPS;

    {   // prologue: stage V^T tile t0 into buf 0 (one load, one ds_write)
        short8 vv = *(const short8*)(vsrc + t0 * 64);
        *(short8*)&Vt[0][sdh * 72 + sch] = vv;
    }
    __syncthreads();
    int cur = 0;

    for (int kt = t0; kt < t0 + TPS; ++kt) {
        // issue next V^T tile load early (T14: write lands after softmax)
        short8 vv;
        const bool pref = (kt + 1 < t0 + TPS);
        if (pref) vv = *(const short8*)(vsrc + (kt + 1) * 64);

        // S^T[64k x 16q]: K fragments straight from global (coalesced)
        f32x4 st[4];
        #pragma unroll
        for (int t = 0; t < 4; ++t) {
            short8 kf = *(const short8*)(khh + (size_t)(kt * 64 + t * 16 + ql) * 32 + g * 8);
            st[t] = __builtin_amdgcn_mfma_f32_16x16x32_bf16(kf, qf, (f32x4){0,0,0,0}, 0, 0, 0);
        }

        float mloc = -INFINITY;
        #pragma unroll
        for (int t = 0; t < 4; ++t)
            mloc = fmaxf(mloc, fmaxf(fmaxf(st[t][0], st[t][1]), fmaxf(st[t][2], st[t][3])));
        mloc = fmaxf(mloc, __shfl_xor(mloc, 16));
        mloc = fmaxf(mloc, __shfl_xor(mloc, 32));

        // defer-max (T13, log2 units): P bounded by 2^8 when deferred
        if (!__all(mloc <= m + 8.f)) {
            float mnew = fmaxf(m, mloc);
            float corr = exp2f(m - mnew);   // first tile: exp2(-inf)=0
            l *= corr; oa0 *= corr; oa1 *= corr; m = mnew;
        }

        float ll = 0.f;
        unsigned pw[8];
        #pragma unroll
        for (int t = 0; t < 4; ++t) {
            float p0 = exp2f(st[t][0] - m);
            float p1 = exp2f(st[t][1] - m);
            float p2 = exp2f(st[t][2] - m);
            float p3 = exp2f(st[t][3] - m);
            ll += (p0 + p1) + (p2 + p3);
            pw[t * 2 + 0] = cvt_pk_bf16(p0, p1);
            pw[t * 2 + 1] = cvt_pk_bf16(p2, p3);
        }
        ll += __shfl_xor(ll, 16);
        ll += __shfl_xor(ll, 32);
        l += ll;

        #pragma unroll
        for (int t = 0; t < 4; ++t) {
            uint2 w2; w2.x = pw[t * 2 + 0]; w2.y = pw[t * 2 + 1];
            *(uint2*)&Plds[wave][ql * 72 + t * 16 + g * 4] = w2;
        }

        // stage next V^T tile (vmcnt wait hidden under QK+softmax above)
        if (pref) *(short8*)&Vt[cur ^ 1][sdh * 72 + sch] = vv;

        // O^T += V^T · P^T from LDS
        #pragma unroll
        for (int c = 0; c < 2; ++c) {
            short8 pf = *(const short8*)&Plds[wave][ql * 72 + c * 32 + g * 8];
            short8 v0 = *(const short8*)&Vt[cur][ql * 72 + c * 32 + g * 8];
            short8 v1 = *(const short8*)&Vt[cur][(16 + ql) * 72 + c * 32 + g * 8];
            oa0 = __builtin_amdgcn_mfma_f32_16x16x32_bf16(v0, pf, oa0, 0, 0, 0);
            oa1 = __builtin_amdgcn_mfma_f32_16x16x32_bf16(v1, pf, oa1, 0, 0, 0);
        }
        __syncthreads();   // next tile staged; everyone done with Vt[cur]
        cur ^= 1;
    }

    const size_t pidx = ((size_t)hd * NNODE + row) * SPLIT + z;
    unsigned short* pp = po + pidx * 32;
    uint2 r0, r1;
    r0.x = cvt_pk_bf16(oa0[0], oa0[1]); r0.y = cvt_pk_bf16(oa0[2], oa0[3]);
    r1.x = cvt_pk_bf16(oa1[0], oa1[1]); r1.y = cvt_pk_bf16(oa1[2], oa1[3]);
    *(uint2*)&pp[g * 4]      = r0;
    *(uint2*)&pp[16 + g * 4] = r1;
    if (g == 0) { pm[pidx] = m; pl[pidx] = l; }
}

__global__ __launch_bounds__(256) void k_attn_merge(const unsigned short* __restrict__ po,
        const float* __restrict__ pm, const float* __restrict__ pl,
        unsigned short* __restrict__ ob) {
    int idx = blockIdx.x * 256 + threadIdx.x;     // NNODE*HDIM
    int row = idx >> 8, c = idx & 255;
    int hd = c >> 5, dh = c & 31;
    size_t b4 = ((size_t)hd * NNODE + row) * SPLIT;
    float m0 = pm[b4+0], m1 = pm[b4+1], m2 = pm[b4+2], m3 = pm[b4+3];
    float M = fmaxf(fmaxf(m0, m1), fmaxf(m2, m3));
    float w0 = exp2f(m0 - M), w1 = exp2f(m1 - M);
    float w2 = exp2f(m2 - M), w3 = exp2f(m3 - M);
    float L = pl[b4]*w0 + pl[b4+1]*w1 + pl[b4+2]*w2 + pl[b4+3]*w3;
    float v = bf2f(po[(b4+0)*32 + dh])*w0 + bf2f(po[(b4+1)*32 + dh])*w1
            + bf2f(po[(b4+2)*32 + dh])*w2 + bf2f(po[(b4+3)*32 + dh])*w3;
    ob[idx] = bfr(v / L);
}

// ---------------------------------------------------------------------------
// heads layer-2 epilogue: one wave per node; th = [4096][256] pre-relu fp32.
__global__ __launch_bounds__(256) void k_heads2(const float* __restrict__ th,
        const float* __restrict__ fp2w, const float* __restrict__ fp2b,
        const float* __restrict__ pd2w, const float* __restrict__ pd2b,
        float* __restrict__ out) {
    const int wave = threadIdx.x >> 6, lane = threadIdx.x & 63;
    const int n = blockIdx.x * 4 + wave;
    const int half = lane >> 5;        // 0 = fp head, 1 = pd head
    const int li = lane & 31;
    float4 h4 = *(const float4*)&th[(size_t)n * HDIM + half * 128 + li * 4];
    h4.x = fmaxf(h4.x, 0.f); h4.y = fmaxf(h4.y, 0.f);
    h4.z = fmaxf(h4.z, 0.f); h4.w = fmaxf(h4.w, 0.f);
    float lf[3];
    float lp[10];
    #pragma unroll
    for (int j = 0; j < 10; ++j) {
        float partial = 0.f;
        if (half == 0) {
            if (j < 3) {
                float4 wv = *(const float4*)&fp2w[j * 128 + li * 4];
                partial = h4.x*wv.x + h4.y*wv.y + h4.z*wv.z + h4.w*wv.w;
            }
        } else {
            float4 wv = *(const float4*)&pd2w[j * 128 + li * 4];
            partial = h4.x*wv.x + h4.y*wv.y + h4.z*wv.z + h4.w*wv.w;
        }
        #pragma unroll
        for (int d = 1; d < 32; d <<= 1) partial += __shfl_xor(partial, d);
        if (j < 3) lf[j] = partial;
        lp[j] = partial;
    }
    if (lane == 0) {
        float l0 = lf[0] + fp2b[0], l1 = lf[1] + fp2b[1], l2 = lf[2] + fp2b[2];
        float mx = fmaxf(l0, fmaxf(l1, l2));
        float e0 = __expf(l0 - mx), e1 = __expf(l1 - mx), e2 = __expf(l2 - mx);
        float inv = 1.f / (e0 + e1 + e2);
        out[(size_t)n * 3 + 0] = e0 * inv;
        out[(size_t)n * 3 + 1] = e1 * inv;
        out[(size_t)n * 3 + 2] = e2 * inv;
    } else if (lane == 32) {
        #pragma unroll
        for (int j = 0; j < 10; ++j)
            out[(size_t)NNODE * 3 + (size_t)n * 10 + j] =
                1.f / (1.f + __expf(-(lp[j] + pd2b[j])));
    }
}

// ---------------------------------------------------------------------------
extern "C" void kernel_launch(void* const* d_in, const int* in_sizes, int n_in,
                              void* d_out, int out_size, void* d_ws, size_t ws_size,
                              hipStream_t stream) {
    const float* x    = (const float*)d_in[0];
    const int*   ei   = (const int*)  d_in[1];
    const float* W1   = (const float*)d_in[2];
    const float* b1   = (const float*)d_in[3];
    const float* W2   = (const float*)d_in[4];
    const float* b2   = (const float*)d_in[5];
    const float* W3   = (const float*)d_in[6];
    const float* b3   = (const float*)d_in[7];
    const float* in_w = (const float*)d_in[8];
    const float* in_b = (const float*)d_in[9];
    const float* outw = (const float*)d_in[10];
    const float* outb = (const float*)d_in[11];
    const float* fp1w = (const float*)d_in[12];
    const float* fp1b = (const float*)d_in[13];
    const float* fp2w = (const float*)d_in[14];
    const float* fp2b = (const float*)d_in[15];
    const float* pd1w = (const float*)d_in[16];
    const float* pd1b = (const float*)d_in[17];
    const float* pd2w = (const float*)d_in[18];
    const float* pd2b = (const float*)d_in[19];
    float* out = (float*)d_out;

    const int E = in_sizes[1] / 2;

    // workspace layout (256B-aligned chunks)
    char* w = (char*)d_ws;
    auto alloc = [&](size_t bytes) {
        char* p = w; w += (bytes + 255) & ~(size_t)255; return p;
    };
    int*   degi   = (int*)alloc(NNODE * 4);
    int*   off    = (int*)alloc(NNODE * 4);
    int*   cursor = (int*)alloc(NNODE * 4);
    int*   csr    = (int*)alloc((size_t)E * 4);
    float* dinv   = (float*)alloc(NNODE * 4);
    float* invdeg = (float*)alloc(NNODE * 4);
    unsigned short* W1t   = (unsigned short*)alloc(256 * 128 * 2);
    unsigned short* W2t   = (unsigned short*)alloc(256 * 256 * 2);
    unsigned short* W3t   = (unsigned short*)alloc(256 * 256 * 2);
    unsigned short* in_wb = (unsigned short*)alloc(768 * 256 * 2);
    unsigned short* outwb = (unsigned short*)alloc(256 * 256 * 2);
    unsigned short* wcatb = (unsigned short*)alloc(256 * 256 * 2);
    float* bcat  = (float*)alloc(256 * 4);
    unsigned short* xb    = (unsigned short*)alloc((size_t)NNODE * DIN * 2);
    float* bufA  = (float*)alloc((size_t)NNODE * HDIM * 4);             // heads th
    unsigned short* bufAb = (unsigned short*)alloc((size_t)NNODE * HDIM * 2); // conv hW
    unsigned short* aggb1 = (unsigned short*)alloc((size_t)NNODE * HDIM * 2);
    unsigned short* aggb2 = (unsigned short*)alloc((size_t)NNODE * HDIM * 2);
    float* hf    = (float*)alloc((size_t)NNODE * HDIM * 4);             // h fp32 residual
    unsigned short* hb    = (unsigned short*)alloc((size_t)NNODE * HDIM * 2);
    unsigned short* qh    = (unsigned short*)alloc((size_t)HEADS * NNODE * 32 * 2);
    unsigned short* kh    = (unsigned short*)alloc((size_t)HEADS * NNODE * 32 * 2);
    unsigned short* vt    = (unsigned short*)alloc((size_t)HEADS * 32 * NNODE * 2);
    unsigned short* po    = (unsigned short*)alloc((size_t)HEADS * NNODE * SPLIT * 32 * 2);
    float* pm    = (float*)alloc((size_t)HEADS * NNODE * SPLIT * 4);
    float* pl    = (float*)alloc((size_t)HEADS * NNODE * SPLIT * 4);
    unsigned short* ob    = (unsigned short*)alloc((size_t)NNODE * HDIM * 2);
    unsigned short* hfinb = (unsigned short*)alloc((size_t)NNODE * HDIM * 2);

    // CSR build + norms + weight/x prep
    hipMemsetAsync(degi, 0, NNODE * sizeof(int), stream);
    k_deg<<<(E + 255) / 256, 256, 0, stream>>>(ei, degi, E);
    k_scan_norm<<<1, 256, 0, stream>>>(degi, off, cursor, dinv, invdeg);
    k_fill<<<(E + 255) / 256, 256, 0, stream>>>(ei, cursor, csr, E);
    k_prep<<<2176, 256, 0, stream>>>(W1, W2, W3, in_w, outw, fp1w, pd1w, fp1b, pd1b, x,
                                     W1t, W2t, W3t, in_wb, outwb, wcatb, bcat, xb);

    dim3 g256(HDIM / 32, NNODE / 64);   // (8,64)
    dim3 g768(768 / 32, NNODE / 64);    // (24,64)

    // conv1
    k_bgemm<DIN, 1, false, false><<<g256, 256, 0, stream>>>(xb, W1t, nullptr, nullptr, bufAb, nullptr, nullptr, HDIM);
    k_gather<0><<<NNODE, 256, 0, stream>>>(bufAb, csr, off, degi, dinv, invdeg, b1, nullptr, aggb1);
    // conv2
    k_bgemm<HDIM, 1, false, false><<<g256, 256, 0, stream>>>(aggb1, W2t, nullptr, nullptr, bufAb, nullptr, nullptr, HDIM);
    k_gather<0><<<NNODE, 256, 0, stream>>>(bufAb, csr, off, degi, dinv, invdeg, b2, nullptr, aggb2);
    // conv3
    k_bgemm<HDIM, 1, false, false><<<g256, 256, 0, stream>>>(aggb2, W3t, nullptr, nullptr, bufAb, nullptr, nullptr, HDIM);
    k_gather<1><<<NNODE, 256, 0, stream>>>(bufAb, csr, off, degi, dinv, invdeg, b3, hf, hb);

    // MHA: qkv GEMM writes q/k head-major + V TRANSPOSED (log2-domain q)
    k_bgemm<HDIM, 2, true, false><<<g768, 256, 0, stream>>>(hb, in_wb, in_b, nullptr, qh, kh, vt, 768);
    k_attn_mfma<<<HEADS * SPLIT * (NNODE / 64), 256, 0, stream>>>(qh, kh, vt, po, pm, pl);
    k_attn_merge<<<(NNODE * HDIM) / 256, 256, 0, stream>>>(po, pm, pl, ob);
    // out-proj + residual -> bf16 h_final
    k_bgemm<HDIM, 1, true, true><<<g256, 256, 0, stream>>>(ob, outwb, outb, hf, hfinb, nullptr, nullptr, HDIM);

    // MLP heads: layer 1 as GEMM (fp32 out), layer 2 epilogue
    k_bgemm<HDIM, 0, true, false><<<g256, 256, 0, stream>>>(hfinb, wcatb, bcat, nullptr, bufA, nullptr, nullptr, HDIM);
    k_heads2<<<NNODE / 4, 256, 0, stream>>>(bufA, fp2w, fp2b, pd2w, pd2b, out);
}

// Round 9
// 183.699 us; speedup vs baseline: 1.3371x; 1.1236x over previous
//
#include <hip/hip_runtime.h>
#include <math.h>

static constexpr int NNODE = 4096;
static constexpr int HDIM  = 256;
static constexpr int DIN   = 128;
static constexpr int HEADS = 8;
static constexpr int SPLIT = 4;     // attention key-split

using short8 = __attribute__((ext_vector_type(8))) short;
using f32x4  = __attribute__((ext_vector_type(4))) float;

__device__ inline unsigned short bfr(float x) {   // RNE fp32->bf16
    union { float f; unsigned u; } v; v.f = x;
    unsigned r = v.u + 0x7FFFu + ((v.u >> 16) & 1u);
    return (unsigned short)(r >> 16);
}
__device__ inline float bf2f(unsigned short u) {
    union { unsigned u; float f; } v; v.u = (unsigned)u << 16; return v.f;
}
__device__ inline unsigned cvt_pk_bf16(float lo, float hi) {
    unsigned r;
    asm("v_cvt_pk_bf16_f32 %0, %1, %2" : "=v"(r) : "v"(lo), "v"(hi));
    return r;
}
__device__ inline float ex2(float x) {            // bare v_exp_f32 (exp2)
    float r;
    asm("v_exp_f32 %0, %1" : "=v"(r) : "v"(x));
    return r;
}

// scale/sqrt(32) folded with log2(e): softmax computed in exp2 domain
static constexpr float QSCALE_LOG2 = 0.25503527f;   // 0.176776695 * 1.442695041

// ---------------------------------------------------------------------------
__global__ void k_deg(const int* __restrict__ ei, int* __restrict__ degi, int E) {
    int e = blockIdx.x * 256 + threadIdx.x;
    if (e < E) atomicAdd(&degi[ei[E + e]], 1);
}

__global__ __launch_bounds__(256) void k_scan_norm(const int* __restrict__ degi,
        int* __restrict__ off, int* __restrict__ cursor,
        float* __restrict__ dinv, float* __restrict__ invdeg) {
    __shared__ int partial[256];
    int t = threadIdx.x;
    int local[16];
    int s = 0;
    #pragma unroll
    for (int i = 0; i < 16; ++i) { local[i] = degi[t * 16 + i]; s += local[i]; }
    partial[t] = s;
    __syncthreads();
    // Hillis-Steele inclusive scan over 256 partials
    #pragma unroll
    for (int d = 1; d < 256; d <<= 1) {
        int add = (t >= d) ? partial[t - d] : 0;
        __syncthreads();
        partial[t] += add;
        __syncthreads();
    }
    int b = partial[t] - s;    // exclusive base for this thread's 16 nodes
    #pragma unroll
    for (int i = 0; i < 16; ++i) {
        int n = t * 16 + i;
        off[n] = b; cursor[n] = b; b += local[i];
        float d = (float)local[i] + 1.0f;
        dinv[n]   = rsqrtf(d);
        invdeg[n] = 1.0f / d;
    }
}

__global__ void k_fill(const int* __restrict__ ei, int* __restrict__ cursor,
                       int* __restrict__ csr, int E) {
    int e = blockIdx.x * 256 + threadIdx.x;
    if (e < E) {
        int d = ei[E + e];
        int p = atomicAdd(&cursor[d], 1);
        csr[p] = ei[e];
    }
}

// ---------------------------------------------------------------------------
// weight + x prep: bf16 convert (+ transpose GCN weights to [N][K]),
// concat fp1/pd1. Grid covers 557056 virtual slots.
__global__ __launch_bounds__(256) void k_prep(
        const float* __restrict__ W1, const float* __restrict__ W2,
        const float* __restrict__ W3, const float* __restrict__ in_w,
        const float* __restrict__ outw, const float* __restrict__ fp1w,
        const float* __restrict__ pd1w, const float* __restrict__ fp1b,
        const float* __restrict__ pd1b, const float* __restrict__ x,
        unsigned short* __restrict__ W1t, unsigned short* __restrict__ W2t,
        unsigned short* __restrict__ W3t, unsigned short* __restrict__ in_wb,
        unsigned short* __restrict__ outwb, unsigned short* __restrict__ wcatb,
        float* __restrict__ bcat, unsigned short* __restrict__ xb) {
    int idx = blockIdx.x * 256 + threadIdx.x;
    if (idx < 32768) {                       // W1 [128][256] -> W1t [256][128]
        int c = idx >> 7, k = idx & 127;
        W1t[idx] = bfr(W1[(size_t)k * 256 + c]);
    } else if (idx < 98304) {                // W2 [256][256] -> W2t
        int j = idx - 32768; int c = j >> 8, k = j & 255;
        W2t[j] = bfr(W2[(size_t)k * 256 + c]);
    } else if (idx < 163840) {
        int j = idx - 98304; int c = j >> 8, k = j & 255;
        W3t[j] = bfr(W3[(size_t)k * 256 + c]);
    } else if (idx < 360448) {               // in_w already [768][256]
        int j = idx - 163840;
        in_wb[j] = bfr(in_w[j]);
    } else if (idx < 425984) {               // outw already [256][256]
        int j = idx - 360448;
        outwb[j] = bfr(outw[j]);
    } else if (idx < 491520) {               // wcat = [fp1w; pd1w]
        int j = idx - 425984;
        int row = j >> 8, k = j & 255;
        wcatb[j] = bfr(row < 128 ? fp1w[(size_t)row * 256 + k]
                                 : pd1w[(size_t)(row - 128) * 256 + k]);
        if (j < 256) bcat[j] = (j < 128) ? fp1b[j] : pd1b[j - 128];
    } else if (idx < 557056) {               // x -> bf16, 8 elems/thread
        int i = (idx - 491520) * 8;
        float4 a = *(const float4*)&x[i];
        float4 b = *(const float4*)&x[i + 4];
        short8 o;
        o[0]=(short)bfr(a.x); o[1]=(short)bfr(a.y); o[2]=(short)bfr(a.z); o[3]=(short)bfr(a.w);
        o[4]=(short)bfr(b.x); o[5]=(short)bfr(b.y); o[6]=(short)bfr(b.z); o[7]=(short)bfr(b.w);
        *(short8*)&xb[i] = o;
    }
}

// ---------------------------------------------------------------------------
// bf16 MFMA GEMM: C[M=4096][Nout] = A_bf16 @ B_bf16^T (+bias) (+addsrc)
// A: [M][K] bf16. B: [Nout][K] bf16 (torch layout).
// Block 256 = 4 waves; block tile 64(M) x 32(N); wave tile 16 x 32.
// EPI: 0 = fp32 out, 1 = bf16 out,
// EPI 2 = qkv: q,k head-major [head][node][32] (q pre-scaled log2);
//              v TRANSPOSED [head][dh][node] (uint2 packed writes).
template<int K, int EPI, bool BIAS, bool ADD>
__global__ __launch_bounds__(256) void k_bgemm(
        const unsigned short* __restrict__ A, const unsigned short* __restrict__ B,
        const float* __restrict__ bias, const float* __restrict__ addsrc,
        void* __restrict__ P0, void* __restrict__ P1, void* __restrict__ P2,
        int Nout) {
    const int lane = threadIdx.x & 63, wave = threadIdx.x >> 6;
    const int ql = lane & 15, g = lane >> 4;
    const int m0w = blockIdx.y * 64 + wave * 16;
    const int n0 = blockIdx.x * 32;
    const unsigned short* ap = A + (size_t)(m0w + ql) * K + g * 8;
    const unsigned short* bp = B + (size_t)(n0 + ql) * K + g * 8;

    f32x4 acc[2] = {{0,0,0,0},{0,0,0,0}};
    #pragma unroll
    for (int k0 = 0; k0 < K; k0 += 32) {
        short8 a = *(const short8*)(ap + k0);
        #pragma unroll
        for (int nt = 0; nt < 2; ++nt) {
            short8 b = *(const short8*)(bp + (size_t)nt * 16 * K + k0);
            acc[nt] = __builtin_amdgcn_mfma_f32_16x16x32_bf16(a, b, acc[nt], 0, 0, 0);
        }
    }
    #pragma unroll
    for (int nt = 0; nt < 2; ++nt) {
        const int col = n0 + nt * 16 + ql;
        const float bv = BIAS ? bias[col] : 0.f;
        if (EPI == 2) {
            const int sec = col >> 8, cc = col & 255;
            const int head = cc >> 5, dh = cc & 31;
            if (sec == 2) {
                // V^T [head][dh][node]: rows m0w+g*4..+3 contiguous -> uint2
                unsigned short* dst = (unsigned short*)P2
                    + ((size_t)head * 32 + dh) * NNODE + m0w + g * 4;
                uint2 pk;
                pk.x = cvt_pk_bf16(acc[nt][0] + bv, acc[nt][1] + bv);
                pk.y = cvt_pk_bf16(acc[nt][2] + bv, acc[nt][3] + bv);
                *(uint2*)dst = pk;
            } else {
                unsigned short* dst = (unsigned short*)(sec == 0 ? P0 : P1);
                const float sc = (sec == 0) ? QSCALE_LOG2 : 1.0f;
                #pragma unroll
                for (int i = 0; i < 4; ++i) {
                    int row = m0w + g * 4 + i;
                    dst[((size_t)head * NNODE + row) * 32 + dh] = bfr((acc[nt][i] + bv) * sc);
                }
            }
        } else if (EPI == 1) {
            unsigned short* Cb = (unsigned short*)P0;
            #pragma unroll
            for (int i = 0; i < 4; ++i) {
                int row = m0w + g * 4 + i;
                float v = acc[nt][i] + bv;
                if (ADD) v += addsrc[(size_t)row * Nout + col];
                Cb[(size_t)row * Nout + col] = bfr(v);
            }
        } else {
            float* Cf = (float*)P0;
            #pragma unroll
            for (int i = 0; i < 4; ++i) {
                int row = m0w + g * 4 + i;
                float v = acc[nt][i] + bv;
                if (ADD) v += addsrc[(size_t)row * Nout + col];
                Cf[(size_t)row * Nout + col] = v;
            }
        }
    }
}

// ---------------------------------------------------------------------------
// CSR gather over bf16 hW. MODE 0: write bf16(relu(val)). MODE 1: fp32 + bf16.
template<int MODE>
__global__ __launch_bounds__(256) void k_gather(const unsigned short* __restrict__ hW,
        const int* __restrict__ csr, const int* __restrict__ off,
        const int* __restrict__ degi, const float* __restrict__ dinv,
        const float* __restrict__ invdeg, const float* __restrict__ bias,
        float* __restrict__ aggf, unsigned short* __restrict__ aggb) {
    const int n = blockIdx.x;
    const int c = threadIdx.x;
    const int start = off[n];
    const int cnt = degi[n];
    __shared__ int   sidx[64];
    __shared__ float swht[64];
    float acc = 0.f;
    for (int k0 = 0; k0 < cnt; k0 += 64) {
        __syncthreads();
        if (c < 64 && k0 + c < cnt) {
            int s = csr[start + k0 + c];
            sidx[c] = s;
            swht[c] = dinv[s];
        }
        __syncthreads();
        int lim = min(64, cnt - k0);
        for (int k = 0; k < lim; ++k)
            acc += bf2f(hW[(size_t)sidx[k] * HDIM + c]) * swht[k];
    }
    float val = acc * dinv[n] + bf2f(hW[(size_t)n * HDIM + c]) * invdeg[n] + bias[c];
    if (MODE == 0) {
        aggb[(size_t)n * HDIM + c] = bfr(fmaxf(val, 0.f));
    } else {
        aggf[(size_t)n * HDIM + c] = val;
        aggb[(size_t)n * HDIM + c] = bfr(val);
    }
}

// ---------------------------------------------------------------------------
// MFMA flash attention, split-K. Flat grid, head = bid&7 (XCD L2 affinity).
// 32 q-rows per wave (2 Q fragments): K loads + V LDS reads shared across
// both q-halves. Raw v_exp_f32 softmax in log2 domain; s_setprio on MFMA.
__global__ __launch_bounds__(256, 4) void k_attn_mfma(const unsigned short* __restrict__ qh,
        const unsigned short* __restrict__ kh, const unsigned short* __restrict__ vt,
        unsigned short* __restrict__ po, float* __restrict__ pm, float* __restrict__ pl) {
    const int bid = blockIdx.x;
    const int hd = bid & 7;                     // XCD affinity: head h -> XCD h
    const int z  = (bid >> 3) & (SPLIT - 1);
    const int qb = bid >> 5;                    // 0..31 (128 q per block)
    const int tid = threadIdx.x;
    const int wave = tid >> 6, lane = tid & 63;
    const int ql = lane & 15, g = lane >> 4;

    __shared__ unsigned short Vt[2][32 * 72];     // [dh][key] pad 72
    __shared__ unsigned short Plds[4][32 * 72];   // per wave [q(32)][key] pad 72

    const unsigned short* khh = kh + (size_t)hd * NNODE * 32;
    const unsigned short* vtt = vt + (size_t)hd * 32 * NNODE;
    const int row0 = qb * 128 + wave * 32 + ql;   // q half 0
    const int row1 = row0 + 16;                   // q half 1
    short8 qf0 = *(const short8*)(qh + ((size_t)hd * NNODE + row0) * 32 + g * 8);
    short8 qf1 = *(const short8*)(qh + ((size_t)hd * NNODE + row1) * 32 + g * 8);

    f32x4 oa00 = {0,0,0,0}, oa01 = {0,0,0,0};     // half0: dh 0-15, 16-31
    f32x4 oa10 = {0,0,0,0}, oa11 = {0,0,0,0};     // half1
    float m0 = -INFINITY, l0 = 0.f, m1 = -INFINITY, l1 = 0.f;

    // V^T staging: thread -> dh = tid>>3 (0..31), chunk = tid&7 (0..7)
    const int sdh = tid >> 3, sch = (tid & 7) * 8;
    const unsigned short* vsrc = vtt + (size_t)sdh * NNODE + sch;
    const unsigned short* kbase = khh + (size_t)ql * 32 + g * 8;
    const int TPS = NNODE / 64 / SPLIT;
    const int t0 = z * TPS;

    {   // prologue: stage V^T tile t0 into buf 0
        short8 vv = *(const short8*)(vsrc + t0 * 64);
        *(short8*)&Vt[0][sdh * 72 + sch] = vv;
    }
    __syncthreads();
    int cur = 0;

    for (int kt = t0; kt < t0 + TPS; ++kt) {
        // issue next V^T tile load early (write lands after softmax)
        short8 vv;
        const bool pref = (kt + 1 < t0 + TPS);
        if (pref) vv = *(const short8*)(vsrc + (kt + 1) * 64);

        // S^T[64k x 16q] x2 halves: K fragments shared
        f32x4 st0[4], st1[4];
        __builtin_amdgcn_s_setprio(1);
        #pragma unroll
        for (int t = 0; t < 4; ++t) {
            short8 kf = *(const short8*)(kbase + ((size_t)kt * 64 + t * 16) * 32);
            st0[t] = __builtin_amdgcn_mfma_f32_16x16x32_bf16(kf, qf0, (f32x4){0,0,0,0}, 0, 0, 0);
            st1[t] = __builtin_amdgcn_mfma_f32_16x16x32_bf16(kf, qf1, (f32x4){0,0,0,0}, 0, 0, 0);
        }
        __builtin_amdgcn_s_setprio(0);

        // ---- softmax half 0 ----
        {
            float mloc = -INFINITY;
            #pragma unroll
            for (int t = 0; t < 4; ++t)
                mloc = fmaxf(mloc, fmaxf(fmaxf(st0[t][0], st0[t][1]), fmaxf(st0[t][2], st0[t][3])));
            mloc = fmaxf(mloc, __shfl_xor(mloc, 16));
            mloc = fmaxf(mloc, __shfl_xor(mloc, 32));
            if (!__all(mloc <= m0 + 8.f)) {            // defer-max (T13)
                float mnew = fmaxf(m0, mloc);
                float corr = ex2(m0 - mnew);
                l0 *= corr; oa00 *= corr; oa01 *= corr; m0 = mnew;
            }
            float ll = 0.f;
            #pragma unroll
            for (int t = 0; t < 4; ++t) {
                float p0 = ex2(st0[t][0] - m0);
                float p1 = ex2(st0[t][1] - m0);
                float p2 = ex2(st0[t][2] - m0);
                float p3 = ex2(st0[t][3] - m0);
                ll += (p0 + p1) + (p2 + p3);
                uint2 w2; w2.x = cvt_pk_bf16(p0, p1); w2.y = cvt_pk_bf16(p2, p3);
                *(uint2*)&Plds[wave][ql * 72 + t * 16 + g * 4] = w2;
            }
            ll += __shfl_xor(ll, 16);
            ll += __shfl_xor(ll, 32);
            l0 += ll;
        }
        // ---- softmax half 1 ----
        {
            float mloc = -INFINITY;
            #pragma unroll
            for (int t = 0; t < 4; ++t)
                mloc = fmaxf(mloc, fmaxf(fmaxf(st1[t][0], st1[t][1]), fmaxf(st1[t][2], st1[t][3])));
            mloc = fmaxf(mloc, __shfl_xor(mloc, 16));
            mloc = fmaxf(mloc, __shfl_xor(mloc, 32));
            if (!__all(mloc <= m1 + 8.f)) {
                float mnew = fmaxf(m1, mloc);
                float corr = ex2(m1 - mnew);
                l1 *= corr; oa10 *= corr; oa11 *= corr; m1 = mnew;
            }
            float ll = 0.f;
            #pragma unroll
            for (int t = 0; t < 4; ++t) {
                float p0 = ex2(st1[t][0] - m1);
                float p1 = ex2(st1[t][1] - m1);
                float p2 = ex2(st1[t][2] - m1);
                float p3 = ex2(st1[t][3] - m1);
                ll += (p0 + p1) + (p2 + p3);
                uint2 w2; w2.x = cvt_pk_bf16(p0, p1); w2.y = cvt_pk_bf16(p2, p3);
                *(uint2*)&Plds[wave][(16 + ql) * 72 + t * 16 + g * 4] = w2;
            }
            ll += __shfl_xor(ll, 16);
            ll += __shfl_xor(ll, 32);
            l1 += ll;
        }

        // stage next V^T tile (vmcnt wait hidden under QK+softmax above)
        if (pref) *(short8*)&Vt[cur ^ 1][sdh * 72 + sch] = vv;

        // O^T += V^T · P^T: V fragments shared across both q-halves
        __builtin_amdgcn_s_setprio(1);
        #pragma unroll
        for (int c = 0; c < 2; ++c) {
            short8 v0  = *(const short8*)&Vt[cur][ql * 72 + c * 32 + g * 8];
            short8 v1  = *(const short8*)&Vt[cur][(16 + ql) * 72 + c * 32 + g * 8];
            short8 pf0 = *(const short8*)&Plds[wave][ql * 72 + c * 32 + g * 8];
            short8 pf1 = *(const short8*)&Plds[wave][(16 + ql) * 72 + c * 32 + g * 8];
            oa00 = __builtin_amdgcn_mfma_f32_16x16x32_bf16(v0, pf0, oa00, 0, 0, 0);
            oa01 = __builtin_amdgcn_mfma_f32_16x16x32_bf16(v1, pf0, oa01, 0, 0, 0);
            oa10 = __builtin_amdgcn_mfma_f32_16x16x32_bf16(v0, pf1, oa10, 0, 0, 0);
            oa11 = __builtin_amdgcn_mfma_f32_16x16x32_bf16(v1, pf1, oa11, 0, 0, 0);
        }
        __builtin_amdgcn_s_setprio(0);
        __syncthreads();   // next tile staged; everyone done with Vt[cur]
        cur ^= 1;
    }

    const size_t pidx0 = ((size_t)hd * NNODE + row0) * SPLIT + z;
    const size_t pidx1 = ((size_t)hd * NNODE + row1) * SPLIT + z;
    unsigned short* pp0 = po + pidx0 * 32;
    unsigned short* pp1 = po + pidx1 * 32;
    uint2 r;
    r.x = cvt_pk_bf16(oa00[0], oa00[1]); r.y = cvt_pk_bf16(oa00[2], oa00[3]);
    *(uint2*)&pp0[g * 4] = r;
    r.x = cvt_pk_bf16(oa01[0], oa01[1]); r.y = cvt_pk_bf16(oa01[2], oa01[3]);
    *(uint2*)&pp0[16 + g * 4] = r;
    r.x = cvt_pk_bf16(oa10[0], oa10[1]); r.y = cvt_pk_bf16(oa10[2], oa10[3]);
    *(uint2*)&pp1[g * 4] = r;
    r.x = cvt_pk_bf16(oa11[0], oa11[1]); r.y = cvt_pk_bf16(oa11[2], oa11[3]);
    *(uint2*)&pp1[16 + g * 4] = r;
    if (g == 0) { pm[pidx0] = m0; pl[pidx0] = l0; pm[pidx1] = m1; pl[pidx1] = l1; }
}

__global__ __launch_bounds__(256) void k_attn_merge(const unsigned short* __restrict__ po,
        const float* __restrict__ pm, const float* __restrict__ pl,
        unsigned short* __restrict__ ob) {
    int idx = blockIdx.x * 256 + threadIdx.x;     // NNODE*HDIM
    int row = idx >> 8, c = idx & 255;
    int hd = c >> 5, dh = c & 31;
    size_t b4 = ((size_t)hd * NNODE + row) * SPLIT;
    float m0 = pm[b4+0], m1 = pm[b4+1], m2 = pm[b4+2], m3 = pm[b4+3];
    float M = fmaxf(fmaxf(m0, m1), fmaxf(m2, m3));
    float w0 = ex2(m0 - M), w1 = ex2(m1 - M);
    float w2 = ex2(m2 - M), w3 = ex2(m3 - M);
    float L = pl[b4]*w0 + pl[b4+1]*w1 + pl[b4+2]*w2 + pl[b4+3]*w3;
    float v = bf2f(po[(b4+0)*32 + dh])*w0 + bf2f(po[(b4+1)*32 + dh])*w1
            + bf2f(po[(b4+2)*32 + dh])*w2 + bf2f(po[(b4+3)*32 + dh])*w3;
    ob[idx] = bfr(v / L);
}

// ---------------------------------------------------------------------------
// heads layer-2 epilogue: one wave per node; th = [4096][256] pre-relu fp32.
__global__ __launch_bounds__(256) void k_heads2(const float* __restrict__ th,
        const float* __restrict__ fp2w, const float* __restrict__ fp2b,
        const float* __restrict__ pd2w, const float* __restrict__ pd2b,
        float* __restrict__ out) {
    const int wave = threadIdx.x >> 6, lane = threadIdx.x & 63;
    const int n = blockIdx.x * 4 + wave;
    const int half = lane >> 5;        // 0 = fp head, 1 = pd head
    const int li = lane & 31;
    float4 h4 = *(const float4*)&th[(size_t)n * HDIM + half * 128 + li * 4];
    h4.x = fmaxf(h4.x, 0.f); h4.y = fmaxf(h4.y, 0.f);
    h4.z = fmaxf(h4.z, 0.f); h4.w = fmaxf(h4.w, 0.f);
    float lf[3];
    float lp[10];
    #pragma unroll
    for (int j = 0; j < 10; ++j) {
        float partial = 0.f;
        if (half == 0) {
            if (j < 3) {
                float4 wv = *(const float4*)&fp2w[j * 128 + li * 4];
                partial = h4.x*wv.x + h4.y*wv.y + h4.z*wv.z + h4.w*wv.w;
            }
        } else {
            float4 wv = *(const float4*)&pd2w[j * 128 + li * 4];
            partial = h4.x*wv.x + h4.y*wv.y + h4.z*wv.z + h4.w*wv.w;
        }
        #pragma unroll
        for (int d = 1; d < 32; d <<= 1) partial += __shfl_xor(partial, d);
        if (j < 3) lf[j] = partial;
        lp[j] = partial;
    }
    if (lane == 0) {
        float l0 = lf[0] + fp2b[0], l1 = lf[1] + fp2b[1], l2 = lf[2] + fp2b[2];
        float mx = fmaxf(l0, fmaxf(l1, l2));
        float e0 = __expf(l0 - mx), e1 = __expf(l1 - mx), e2 = __expf(l2 - mx);
        float inv = 1.f / (e0 + e1 + e2);
        out[(size_t)n * 3 + 0] = e0 * inv;
        out[(size_t)n * 3 + 1] = e1 * inv;
        out[(size_t)n * 3 + 2] = e2 * inv;
    } else if (lane == 32) {
        #pragma unroll
        for (int j = 0; j < 10; ++j)
            out[(size_t)NNODE * 3 + (size_t)n * 10 + j] =
                1.f / (1.f + __expf(-(lp[j] + pd2b[j])));
    }
}

// ---------------------------------------------------------------------------
extern "C" void kernel_launch(void* const* d_in, const int* in_sizes, int n_in,
                              void* d_out, int out_size, void* d_ws, size_t ws_size,
                              hipStream_t stream) {
    const float* x    = (const float*)d_in[0];
    const int*   ei   = (const int*)  d_in[1];
    const float* W1   = (const float*)d_in[2];
    const float* b1   = (const float*)d_in[3];
    const float* W2   = (const float*)d_in[4];
    const float* b2   = (const float*)d_in[5];
    const float* W3   = (const float*)d_in[6];
    const float* b3   = (const float*)d_in[7];
    const float* in_w = (const float*)d_in[8];
    const float* in_b = (const float*)d_in[9];
    const float* outw = (const float*)d_in[10];
    const float* outb = (const float*)d_in[11];
    const float* fp1w = (const float*)d_in[12];
    const float* fp1b = (const float*)d_in[13];
    const float* fp2w = (const float*)d_in[14];
    const float* fp2b = (const float*)d_in[15];
    const float* pd1w = (const float*)d_in[16];
    const float* pd1b = (const float*)d_in[17];
    const float* pd2w = (const float*)d_in[18];
    const float* pd2b = (const float*)d_in[19];
    float* out = (float*)d_out;

    const int E = in_sizes[1] / 2;

    // workspace layout (256B-aligned chunks)
    char* w = (char*)d_ws;
    auto alloc = [&](size_t bytes) {
        char* p = w; w += (bytes + 255) & ~(size_t)255; return p;
    };
    int*   degi   = (int*)alloc(NNODE * 4);
    int*   off    = (int*)alloc(NNODE * 4);
    int*   cursor = (int*)alloc(NNODE * 4);
    int*   csr    = (int*)alloc((size_t)E * 4);
    float* dinv   = (float*)alloc(NNODE * 4);
    float* invdeg = (float*)alloc(NNODE * 4);
    unsigned short* W1t   = (unsigned short*)alloc(256 * 128 * 2);
    unsigned short* W2t   = (unsigned short*)alloc(256 * 256 * 2);
    unsigned short* W3t   = (unsigned short*)alloc(256 * 256 * 2);
    unsigned short* in_wb = (unsigned short*)alloc(768 * 256 * 2);
    unsigned short* outwb = (unsigned short*)alloc(256 * 256 * 2);
    unsigned short* wcatb = (unsigned short*)alloc(256 * 256 * 2);
    float* bcat  = (float*)alloc(256 * 4);
    unsigned short* xb    = (unsigned short*)alloc((size_t)NNODE * DIN * 2);
    float* bufA  = (float*)alloc((size_t)NNODE * HDIM * 4);             // heads th
    unsigned short* bufAb = (unsigned short*)alloc((size_t)NNODE * HDIM * 2); // conv hW
    unsigned short* aggb1 = (unsigned short*)alloc((size_t)NNODE * HDIM * 2);
    unsigned short* aggb2 = (unsigned short*)alloc((size_t)NNODE * HDIM * 2);
    float* hf    = (float*)alloc((size_t)NNODE * HDIM * 4);             // h fp32 residual
    unsigned short* hb    = (unsigned short*)alloc((size_t)NNODE * HDIM * 2);
    unsigned short* qh    = (unsigned short*)alloc((size_t)HEADS * NNODE * 32 * 2);
    unsigned short* kh    = (unsigned short*)alloc((size_t)HEADS * NNODE * 32 * 2);
    unsigned short* vt    = (unsigned short*)alloc((size_t)HEADS * 32 * NNODE * 2);
    unsigned short* po    = (unsigned short*)alloc((size_t)HEADS * NNODE * SPLIT * 32 * 2);
    float* pm    = (float*)alloc((size_t)HEADS * NNODE * SPLIT * 4);
    float* pl    = (float*)alloc((size_t)HEADS * NNODE * SPLIT * 4);
    unsigned short* ob    = (unsigned short*)alloc((size_t)NNODE * HDIM * 2);
    unsigned short* hfinb = (unsigned short*)alloc((size_t)NNODE * HDIM * 2);

    // CSR build + norms + weight/x prep
    hipMemsetAsync(degi, 0, NNODE * sizeof(int), stream);
    k_deg<<<(E + 255) / 256, 256, 0, stream>>>(ei, degi, E);
    k_scan_norm<<<1, 256, 0, stream>>>(degi, off, cursor, dinv, invdeg);
    k_fill<<<(E + 255) / 256, 256, 0, stream>>>(ei, cursor, csr, E);
    k_prep<<<2176, 256, 0, stream>>>(W1, W2, W3, in_w, outw, fp1w, pd1w, fp1b, pd1b, x,
                                     W1t, W2t, W3t, in_wb, outwb, wcatb, bcat, xb);

    dim3 g256(HDIM / 32, NNODE / 64);   // (8,64)
    dim3 g768(768 / 32, NNODE / 64);    // (24,64)

    // conv1
    k_bgemm<DIN, 1, false, false><<<g256, 256, 0, stream>>>(xb, W1t, nullptr, nullptr, bufAb, nullptr, nullptr, HDIM);
    k_gather<0><<<NNODE, 256, 0, stream>>>(bufAb, csr, off, degi, dinv, invdeg, b1, nullptr, aggb1);
    // conv2
    k_bgemm<HDIM, 1, false, false><<<g256, 256, 0, stream>>>(aggb1, W2t, nullptr, nullptr, bufAb, nullptr, nullptr, HDIM);
    k_gather<0><<<NNODE, 256, 0, stream>>>(bufAb, csr, off, degi, dinv, invdeg, b2, nullptr, aggb2);
    // conv3
    k_bgemm<HDIM, 1, false, false><<<g256, 256, 0, stream>>>(aggb2, W3t, nullptr, nullptr, bufAb, nullptr, nullptr, HDIM);
    k_gather<1><<<NNODE, 256, 0, stream>>>(bufAb, csr, off, degi, dinv, invdeg, b3, hf, hb);

    // MHA: qkv GEMM writes q/k head-major + V TRANSPOSED (log2-domain q)
    k_bgemm<HDIM, 2, true, false><<<g768, 256, 0, stream>>>(hb, in_wb, in_b, nullptr, qh, kh, vt, 768);
    k_attn_mfma<<<HEADS * SPLIT * (NNODE / 128), 256, 0, stream>>>(qh, kh, vt, po, pm, pl);
    k_attn_merge<<<(NNODE * HDIM) / 256, 256, 0, stream>>>(po, pm, pl, ob);
    // out-proj + residual -> bf16 h_final
    k_bgemm<HDIM, 1, true, true><<<g256, 256, 0, stream>>>(ob, outwb, outb, hf, hfinb, nullptr, nullptr, HDIM);

    // MLP heads: layer 1 as GEMM (fp32 out), layer 2 epilogue
    k_bgemm<HDIM, 0, true, false><<<g256, 256, 0, stream>>>(hfinb, wcatb, bcat, nullptr, bufA, nullptr, nullptr, HDIM);
    k_heads2<<<NNODE / 4, 256, 0, stream>>>(bufA, fp2w, fp2b, pd2w, pd2b, out);
}